// Round 9
// baseline (6822.028 us; speedup 1.0000x reference)
//
#include <hip/hip_runtime.h>
#include <math.h>

// NER BiLSTM-CRF on MI355X — persistent recurrence, 512-thread blocks, weights in
// VGPRs, fence-free sc0sc1 exchange. fp32 throughout (Viterbi argmax flips fatal).
//
// 256 blocks, 1/CU (98 KB LDS). g=bid&7 (sync group: d=g>>2, bg=g&3, 16 batches),
// ug=bid>>3 (8 units). 512 threads = 8 waves (2/SIMD).
// All cross-block traffic sc0 sc1 (system scope; round-6 lesson: sc0-alone = stale L1).
// All s_waitcnt vmcnt(0) INSIDE the issuing asm block (round-8 lesson: counted
// vmcnt across asm blocks breaks under spill; "=&v" early-clobber mandatory).
//
// Release: pointwise (tid<128, waves 0-1) h stores sc0sc1 -> per-wave vmcnt(0) ->
// tag[ug][half]=tt+1 (half = batch half: wave0 = b0..7, wave1 = b8..15).
// Acquire: thread tid loads h chunk [unit tid>>1, batches (tid&1)*8..+8) from
// block tid>>4, produced by wave tid&1 -> polls that single dword tag.
// Coverage: 512 threads cover all 32x2 producer tags before SYNC_A.
// WAR safe: tag=tt+1 => producer passed SYNC_B(tt) => its buf[par] reads done.
//
// ws: h_glob [8 g][2 par][256 u][16 b] f32  262144 B @ 0
//     tags   [8 g][32 ug][2 half] i32       2048 B   @ 262144
//     h_hist [64 b][512 l][512 h] f32       67108864 @ 267264
//     em     [512][64][9] f32               1179648  @ 67376128
//     last_tag [64] i32                     256      @ 68555776
//     hist   [64][512][9] u8                294912   @ 68556032

#define Bv 64
#define Lv 512

__device__ __forceinline__ float sigmoidf_(float x) { return 1.0f / (1.0f + expf(-x)); }

__global__ __launch_bounds__(512, 2) void lstm_persist(
    const int* __restrict__ x, const float* __restrict__ embed,
    const float* __restrict__ Wih_f, const float* __restrict__ Whh_f, const float* __restrict__ bf,
    const float* __restrict__ Wih_b, const float* __restrict__ Whh_b, const float* __restrict__ bb_,
    float* __restrict__ h_glob, int* __restrict__ tags, float* __restrict__ h_hist)
{
    const int bid = blockIdx.x;
    const int g  = bid & 7;           // sync group
    const int d  = g >> 2;            // direction
    const int bg = g & 3;             // batch group (16 batches)
    const int ug = bid >> 3;          // unit group (8 units)
    const int tid = threadIdx.x;
    const int u0 = ug * 8;
    const int b0 = bg * 16;

    const float* Wih  = d ? Wih_b : Wih_f;
    const float* Whh  = d ? Whh_b : Whh_f;
    const float* bias = d ? bb_   : bf;

    // dot tiling: tid = ks*32 + tr*4 + tb; ks 0..15 (K-window 16), tr 0..7 (unit), tb 0..3
    const int ks = tid >> 5;
    const int tr = (tid >> 2) & 7;
    const int tb = tid & 3;
    const int k0 = ks * 16;

    __shared__ float h_lds[16][260];        // [batch][unit] h(t) gathered
    __shared__ float emb_lds[2][16][260];   // [parity][batch][emb]
    __shared__ int   x_lds[16][512];
    __shared__ float parts[8][32][17];
    __shared__ float bias_lds[32];

    // ---- stage x slab (16 batches x 512 positions) ----
    for (int i = tid; i < 16 * 128; i += 512) {
        const int b = i >> 7, c4 = (i & 127) * 4;
        *reinterpret_cast<int4*>(&x_lds[b][c4]) =
            *reinterpret_cast<const int4*>(x + (size_t)(b0 + b) * Lv + c4);
    }
    if (tid < 32) bias_lds[tid] = bias[(tid >> 3) * 256 + u0 + (tid & 7)];

    // ---- BOTH weight slices to VGPRs: rows {gate i, unit u0+tr}, K [k0,k0+16) ----
    float4 wih[4][4], whh[4][4];
    #pragma unroll
    for (int i = 0; i < 4; ++i) {
        const float* wi = Wih + ((size_t)(i * 256 + u0 + tr)) * 256 + k0;
        const float* wh = Whh + ((size_t)(i * 256 + u0 + tr)) * 256 + k0;
        #pragma unroll
        for (int m = 0; m < 4; ++m) {
            wih[i][m] = *reinterpret_cast<const float4*>(wi + 4 * m);
            whh[i][m] = *reinterpret_cast<const float4*>(wh + 4 * m);
        }
    }
    __syncthreads();   // x_lds ready

    // ---- prologue: emb for step 0 into emb_lds[0] ----
    {
        const int b = tid >> 5, cseg = tid & 31;   // 8 floats each
        const int t0 = d ? (Lv - 1) : 0;
        const float* src = embed + (size_t)x_lds[b][t0] * 256 + cseg * 8;
        float4 s0 = *reinterpret_cast<const float4*>(src);
        float4 s1 = *reinterpret_cast<const float4*>(src + 4);
        float4* dstp = reinterpret_cast<float4*>(&emb_lds[0][b][cseg * 8]);
        dstp[0] = s0; dstp[1] = s1;
    }
    __syncthreads();

    float creg = 0.f;   // cell state for tid<128: unit u0+(tid&7), batch b0+(tid>>3)
    const int* my_tag = tags + ((g * 32 + (tid >> 4)) << 1) + (tid & 1);
    int* rel_tag = tags + ((g * 32 + ug) << 1) + (tid >> 6);   // valid for tid 0,64

    for (int tt = 0; tt < Lv; ++tt) {
        const int par = tt & 1;

        float acc[4][4];
        #pragma unroll
        for (int i = 0; i < 4; ++i)
            #pragma unroll
            for (int u = 0; u < 4; ++u) acc[i][u] = 0.f;

        // ---- 1. gx dot: wih(regs) . emb_lds[par] ----
        #pragma unroll
        for (int m = 0; m < 4; ++m) {
            float4 ev[4];
            #pragma unroll
            for (int u = 0; u < 4; ++u)
                ev[u] = *reinterpret_cast<const float4*>(&emb_lds[par][tb + 4 * u][k0 + 4 * m]);
            #pragma unroll
            for (int i = 0; i < 4; ++i) {
                const float4 wv = wih[i][m];
                #pragma unroll
                for (int u = 0; u < 4; ++u)
                    acc[i][u] += wv.x * ev[u].x + wv.y * ev[u].y + wv.z * ev[u].z + wv.w * ev[u].w;
            }
        }

        // ---- 2. stage emb for tt+1 into emb_lds[par^1] (overlaps poll) ----
        if (tt + 1 < Lv) {
            const int b = tid >> 5, cseg = tid & 31;
            const int t1 = d ? (Lv - 2 - tt) : (tt + 1);
            const float* src = embed + (size_t)x_lds[b][t1] * 256 + cseg * 8;
            float4 s0 = *reinterpret_cast<const float4*>(src);
            float4 s1 = *reinterpret_cast<const float4*>(src + 4);
            float4* dstp = reinterpret_cast<float4*>(&emb_lds[par ^ 1][b][cseg * 8]);
            dstp[0] = s0; dstp[1] = s1;
        }

        // ---- 3. poll own producer tag (1 dword), then fill own 32B h chunk ----
        if (tt > 0) {
            int v; int it = 0;
            for (;;) {
                asm volatile("global_load_dword %0, %1, off sc0 sc1\n\ts_waitcnt vmcnt(0)"
                             : "=&v"(v) : "v"(my_tag) : "memory");
                if (v >= tt) break;
                if (++it > 2) __builtin_amdgcn_s_sleep(2);
                if (it > (1 << 22)) break;   // failsafe (never hit when resident)
            }
            const float* hs = h_glob + ((size_t)(g * 2 + par)) * 4096 + tid * 8;
            float4 a0, a1;
            asm volatile(
                "global_load_dwordx4 %0, %2, off sc0 sc1\n\t"
                "global_load_dwordx4 %1, %2, off offset:16 sc0 sc1\n\t"
                "s_waitcnt vmcnt(0)"
                : "=&v"(a0), "=&v"(a1) : "v"(hs) : "memory");
            __builtin_amdgcn_sched_barrier(0);
            const int u = tid >> 1;
            const int r0 = (tid & 1) * 8;
            h_lds[r0 + 0][u] = a0.x; h_lds[r0 + 1][u] = a0.y;
            h_lds[r0 + 2][u] = a0.z; h_lds[r0 + 3][u] = a0.w;
            h_lds[r0 + 4][u] = a1.x; h_lds[r0 + 5][u] = a1.y;
            h_lds[r0 + 6][u] = a1.z; h_lds[r0 + 7][u] = a1.w;
        }
        __syncthreads();   // SYNC_A: h_lds ready, emb_lds[par^1] ready

        // ---- 4. hh dot: whh(regs) . h_lds ----
        if (tt > 0) {
            #pragma unroll
            for (int m = 0; m < 4; ++m) {
                float4 hv[4];
                #pragma unroll
                for (int u = 0; u < 4; ++u)
                    hv[u] = *reinterpret_cast<const float4*>(&h_lds[tb + 4 * u][k0 + 4 * m]);
                #pragma unroll
                for (int i = 0; i < 4; ++i) {
                    const float4 wv = whh[i][m];
                    #pragma unroll
                    for (int u = 0; u < 4; ++u)
                        acc[i][u] += wv.x * hv[u].x + wv.y * hv[u].y + wv.z * hv[u].z + wv.w * hv[u].w;
                }
            }
        }

        // ---- 5. reduce ksegs: shfl pair (bit5), 8 wave-partials to LDS ----
        #pragma unroll
        for (int i = 0; i < 4; ++i)
            #pragma unroll
            for (int u = 0; u < 4; ++u)
                acc[i][u] += __shfl_xor(acc[i][u], 32);
        if ((tid & 32) == 0) {
            const int w = tid >> 6;
            #pragma unroll
            for (int i = 0; i < 4; ++i)
                #pragma unroll
                for (int u = 0; u < 4; ++u)
                    parts[w][i * 8 + tr][tb + 4 * u] = acc[i][u];
        }
        __syncthreads();   // SYNC_B

        // ---- 6. pointwise on tid<128 (waves 0-1): unit u0+(tid&7), batch b0+(tid>>3) ----
        float hval = 0.f;
        if (tid < 128) {
            const int j  = tid & 7;
            const int bb = tid >> 3;
            float gv[4];
            #pragma unroll
            for (int q = 0; q < 4; ++q) {
                const int r = q * 8 + j;
                float s = bias_lds[r];
                #pragma unroll
                for (int w = 0; w < 8; ++w) s += parts[w][r][bb];
                gv[q] = s;
            }
            creg = sigmoidf_(gv[1]) * creg + sigmoidf_(gv[0]) * tanhf(gv[2]);
            hval = sigmoidf_(gv[3]) * tanhf(creg);
            float* dst = h_glob + ((size_t)(g * 2 + (par ^ 1))) * 4096 + (u0 + j) * 16 + bb;
            asm volatile("global_store_dword %0, %1, off sc0 sc1"
                         :: "v"(dst), "v"(hval) : "memory");
        }
        // per-wave release: own wave's h stores drained -> publish tag
        asm volatile("s_waitcnt vmcnt(0)" ::: "memory");
        if ((tid & 63) == 0 && tid < 128) {
            int val = tt + 1;
            asm volatile("global_store_dword %0, %1, off sc0 sc1"
                         :: "v"(rel_tag), "v"(val) : "memory");
        }
        // h_hist store off the critical path (plain cached store)
        if (tid < 128) {
            const int j  = tid & 7;
            const int bb = tid >> 3;
            const int t_eff = d ? (Lv - 1 - tt) : tt;
            h_hist[((size_t)(b0 + bb) * Lv + t_eff) * 512 + d * 256 + u0 + j] = hval;
        }
    }
}

// emissions: em[l][b][j] = dot(h_hist[b][l][:512], Wout[j]) + bout[j]
__global__ __launch_bounds__(256) void emis_kernel(
    const float* __restrict__ h_hist, const float* __restrict__ Wout,
    const float* __restrict__ bout, float* __restrict__ em)
{
    const int l  = blockIdx.x >> 2;
    const int bg = blockIdx.x & 3;
    const int tid = threadIdx.x;
    __shared__ float w_lds[9][516];
    __shared__ float h_ldsx[16][512];

    for (int i = tid; i < 9 * 512; i += 256) w_lds[i >> 9][i & 511] = Wout[i];
    for (int i = tid; i < 16 * 128; i += 256) {
        const int bb = i >> 7; const int k = (i & 127) * 4;
        *reinterpret_cast<float4*>(&h_ldsx[bb][k]) =
            *reinterpret_cast<const float4*>(&h_hist[((size_t)(bg * 16 + bb) * 512 + l) * 512 + k]);
    }
    __syncthreads();

    const int bb = tid >> 4;
    const int j = tid & 15;
    if (j < 9) {
        float acc = bout[j];
        #pragma unroll 4
        for (int k = 0; k < 512; k += 4) {
            float4 hv = *reinterpret_cast<const float4*>(&h_ldsx[bb][k]);
            float4 wv = *reinterpret_cast<const float4*>(&w_lds[j][k]);
            acc += hv.x * wv.x + hv.y * wv.y + hv.z * wv.z + hv.w * wv.w;
        }
        em[((size_t)l * 64 + bg * 16 + bb) * 9 + j] = acc;
    }
}

__global__ __launch_bounds__(576) void viterbi_fwd(
    const float* __restrict__ em, const float* __restrict__ start,
    const float* __restrict__ trans, const float* __restrict__ endt,
    unsigned char* __restrict__ hist, int* __restrict__ last_tag,
    float* __restrict__ out_best)
{
    const int tid = threadIdx.x;
    const int b = tid / 9;
    const int j = tid - b * 9;
    __shared__ float sc[2][64][9];
    float t9[9];
    #pragma unroll
    for (int i = 0; i < 9; ++i) t9[i] = trans[i * 9 + j];

    sc[0][b][j] = start[j] + em[tid];
    float emv = em[(64 + b) * 9 + j];
    __syncthreads();
    for (int t = 1; t < 512; ++t) {
        float em_nxt = (t < 511) ? em[((t + 1) * 64 + b) * 9 + j] : 0.f;
        const int cur = t & 1, prv = cur ^ 1;
        float best = -1e30f; int arg = 0;
        #pragma unroll
        for (int i = 0; i < 9; ++i) {
            float v = sc[prv][b][i] + t9[i];
            if (v > best) { best = v; arg = i; }
        }
        best += emv;
        sc[cur][b][j] = best;
        hist[((size_t)b * 512 + t) * 9 + j] = (unsigned char)arg;
        __syncthreads();
        emv = em_nxt;
    }
    sc[1][b][j] += endt[j];
    __syncthreads();
    if (j == 0) {
        float best = -1e30f; int arg = 0;
        #pragma unroll
        for (int i = 0; i < 9; ++i) {
            float v = sc[1][b][i];
            if (v > best) { best = v; arg = i; }
        }
        out_best[b] = best;
        last_tag[b] = arg;
    }
}

__global__ __launch_bounds__(256) void backtrack(
    const unsigned char* __restrict__ hist, const int* __restrict__ last_tag,
    float* __restrict__ out_tags)
{
    const int b = blockIdx.x;
    const int tid = threadIdx.x;
    __shared__ __align__(16) unsigned char hl[512 * 9];
    const uint4* src = reinterpret_cast<const uint4*>(hist + (size_t)b * 512 * 9);
    uint4* dst = reinterpret_cast<uint4*>(hl);
    for (int i = tid; i < 512 * 9 / 16; i += 256) dst[i] = src[i];
    __syncthreads();
    if (tid == 0) {
        int tag = last_tag[b];
        out_tags[b * 512 + 511] = (float)tag;
        for (int t = 511; t >= 1; --t) {
            tag = hl[t * 9 + tag];
            out_tags[b * 512 + t - 1] = (float)tag;
        }
    }
}

extern "C" void kernel_launch(void* const* d_in, const int* in_sizes, int n_in,
                              void* d_out, int out_size, void* d_ws, size_t ws_size,
                              hipStream_t stream)
{
    const int*   x     = (const int*)d_in[0];
    const float* embed = (const float*)d_in[1];
    const float* Wih_f = (const float*)d_in[2];
    const float* Whh_f = (const float*)d_in[3];
    const float* bf    = (const float*)d_in[4];
    const float* Wih_b = (const float*)d_in[5];
    const float* Whh_b = (const float*)d_in[6];
    const float* bb    = (const float*)d_in[7];
    const float* Wout  = (const float*)d_in[8];
    const float* bout  = (const float*)d_in[9];
    const float* start = (const float*)d_in[10];
    const float* trans = (const float*)d_in[11];
    const float* endt  = (const float*)d_in[12];

    char* ws = (char*)d_ws;
    float* h_glob  = (float*)ws;                        // 262144 B
    int*   tags    = (int*)(ws + 262144);               // 2048 B
    float* h_hist  = (float*)(ws + 267264);             // 67108864 B
    float* em      = (float*)(ws + 267264 + 67108864);  // @67376128, 1179648 B
    int*   last_tag = (int*)(ws + 68555776);            // 256 B
    unsigned char* hist = (unsigned char*)(ws + 68556032); // 294912 B

    float* out = (float*)d_out;   // [64*512 tags][64 best], all f32

    hipMemsetAsync(tags, 0, 2048, stream);        // tags = 0

    lstm_persist<<<256, 512, 0, stream>>>(x, embed, Wih_f, Whh_f, bf,
                                          Wih_b, Whh_b, bb,
                                          h_glob, tags, h_hist);
    emis_kernel<<<2048, 256, 0, stream>>>(h_hist, Wout, bout, em);
    viterbi_fwd<<<1, 576, 0, stream>>>(em, start, trans, endt, hist, last_tag, out + 64 * 512);
    backtrack<<<64, 256, 0, stream>>>(hist, last_tag, out);
}

// Round 11
// 4454.874 us; speedup vs baseline: 1.5314x; 1.5314x over previous
//
#include <hip/hip_runtime.h>
#include <math.h>

// NER BiLSTM-CRF on MI355X — persistent recurrence with WAVE SPECIALIZATION:
// waves 0-1 compute gx while waves 2-3 do the cross-block h exchange (poll+fill).
// fp32 throughout (Viterbi argmax flips are fatal: tags threshold 4.82, range 0..8).
//
// 256 blocks of 256 threads, 1/CU (~96 KB LDS -> guaranteed residency).
// g=bid&7 (sync group: d=g>>2, bg=g&3, 16 batches), ug=bid>>3 (8 units).
// All cross-block traffic sc0 sc1 (system scope; r6 lesson: sc0-alone = stale L1).
// All asm loads wait vmcnt(0) INSIDE the issuing asm block, outputs early-clobbered
// (r8+r10 lesson: asm-loaded regs must never be carried across compiler-visible code).
//
// Step:
//   [waves 0-1] gx dot (wih LDS . emb) -> shfl -> parts_gx     (SIMDs 0-1, ~0.85us)
//   [waves 2-3] poll own tag -> fill 2 units (asm, wait inside) -> h_lds   (overlap!)
//   SYNC_A
//   [all] stage emb(t+1) (latency hides under hh) ; hh dot -> shfl -> parts_hh
//   SYNC_B
//   [waves 0-1] pointwise: gates = parts_gx + parts_hh + bias; h store sc0sc1
//   drain vmcnt(0) -> tid 0/64 publish wave tag -> h_hist store.
//
// Dependency: fill thread p=tid-128 covers units 2p,2p+1 -> producer block p>>2,
// producer wave (p&3)>>1 -> polls that single tag. 128 threads cover all 64 tags.
// WAR on h_glob parity buffer: Z writes buf B at t+2 only after Z's fill(t+2),
// which needs MY tag value t+2, released after MY step t+1 (fill of B done). Safe.
// h_lds single buffer: hh reads in [SYNC_A(t),SYNC_B(t)]; next fill write is after
// SYNC_B(t) in waves 2-3 program order. Safe.
//
// ws: h_glob [8 g][2 par][256 u][16 b] f32  262144 B @ 0
//     tags   [8 g][32 ug][2 w] i32          2048 B   @ 262144
//     h_hist [64 b][512 l][512 h] f32       67108864 @ 267264
//     em     [512][64][9] f32               1179648  @ 67376128
//     last_tag [64] i32                     256      @ 68555776
//     hist   [64][512][9] u8                294912   @ 68556032

#define Bv 64
#define Lv 512

__device__ __forceinline__ float sigmoidf_(float x) { return 1.0f / (1.0f + expf(-x)); }

__global__ __launch_bounds__(256, 1) void lstm_persist(
    const int* __restrict__ x, const float* __restrict__ embed,
    const float* __restrict__ Wih_f, const float* __restrict__ Whh_f, const float* __restrict__ bf,
    const float* __restrict__ Wih_b, const float* __restrict__ Whh_b, const float* __restrict__ bb_,
    float* __restrict__ h_glob, int* __restrict__ tags, float* __restrict__ h_hist)
{
    const int bid = blockIdx.x;
    const int g  = bid & 7;           // sync group
    const int d  = g >> 2;            // direction
    const int bg = g & 3;             // batch group (16 batches)
    const int ug = bid >> 3;          // unit group (8 units)
    const int tid = threadIdx.x;
    const int u0 = ug * 8;
    const int b0 = bg * 16;

    const float* Wih  = d ? Wih_b : Wih_f;
    const float* Whh  = d ? Whh_b : Whh_f;
    const float* bias = d ? bb_   : bf;

    // hh tiling (all threads): tid = ks*32 + tr*4 + tb, K window [k0h, k0h+32)
    const int tr = (tid >> 2) & 7;
    const int tb = tid & 3;
    const int k0h = (tid >> 5) * 32;

    __shared__ float wih_lds[32][260];
    __shared__ float h_lds[16][260];        // single buffer (WAR ordered by SYNC_B)
    __shared__ float emb_lds[2][16][260];
    __shared__ float parts_hh[4][32][17];
    __shared__ float parts_gx[2][32][17];
    __shared__ float bias_lds[32];

    // ---- stage Wih slice to LDS (all threads) ----
    {
        const int row = tid >> 3;     // 0..31
        const int seg = tid & 7;      // 32 floats each
        const int gq = row >> 3, j = row & 7;
        const float4* src = reinterpret_cast<const float4*>(
            Wih + ((size_t)(gq * 256 + u0 + j)) * 256 + seg * 32);
        float4* dst = reinterpret_cast<float4*>(&wih_lds[row][seg * 32]);
        #pragma unroll
        for (int q = 0; q < 8; ++q) dst[q] = src[q];
    }
    if (tid < 32) bias_lds[tid] = bias[(tid >> 3) * 256 + u0 + (tid & 7)];

    // ---- Whh slice to registers: rows {i*256+u0+tr}, K [k0h, k0h+32) ----
    float4 whh[4][8];
    #pragma unroll
    for (int i = 0; i < 4; ++i) {
        const float* wr = Whh + ((size_t)(i * 256 + u0 + tr)) * 256 + k0h;
        #pragma unroll
        for (int m = 0; m < 8; ++m) whh[i][m] = *reinterpret_cast<const float4*>(wr + 4 * m);
    }

    // ---- prologue: emb for step 0 into emb_lds[0] (all threads) ----
    {
        const int b = tid >> 4, cseg = tid & 15;
        const int t0 = d ? (Lv - 1) : 0;
        const int xv = x[(b0 + b) * Lv + t0];
        const float4* src = reinterpret_cast<const float4*>(embed + (size_t)xv * 256 + cseg * 16);
        float4* dstp = reinterpret_cast<float4*>(&emb_lds[0][b][cseg * 16]);
        dstp[0] = src[0]; dstp[1] = src[1]; dstp[2] = src[2]; dstp[3] = src[3];
    }
    __syncthreads();

    float creg = 0.f;   // cell state for tid<128: unit u0+(tid>>4), batch b0+(tid&15)
    int* rel_tag = tags + ((g * 32 + ug) << 1) + (tid >> 6);   // used by tid 0, 64

    for (int tt = 0; tt < Lv; ++tt) {
        const int par = tt & 1;

        if (tid < 128) {
            // ---- gx dot on waves 0-1: each thread 2 ksegs (K window 64) ----
            const int k0g = (tid >> 5) * 64;
            float accg[4][4];
            #pragma unroll
            for (int i = 0; i < 4; ++i)
                #pragma unroll
                for (int u = 0; u < 4; ++u) accg[i][u] = 0.f;
            #pragma unroll
            for (int m = 0; m < 16; ++m) {
                float4 ev[4];
                #pragma unroll
                for (int u = 0; u < 4; ++u)
                    ev[u] = *reinterpret_cast<const float4*>(&emb_lds[par][tb + 4 * u][k0g + 4 * m]);
                #pragma unroll
                for (int i = 0; i < 4; ++i) {
                    float4 wv = *reinterpret_cast<const float4*>(&wih_lds[tr + 8 * i][k0g + 4 * m]);
                    #pragma unroll
                    for (int u = 0; u < 4; ++u)
                        accg[i][u] += wv.x * ev[u].x + wv.y * ev[u].y + wv.z * ev[u].z + wv.w * ev[u].w;
                }
            }
            #pragma unroll
            for (int i = 0; i < 4; ++i)
                #pragma unroll
                for (int u = 0; u < 4; ++u)
                    accg[i][u] += __shfl_xor(accg[i][u], 32);
            if ((tid & 32) == 0) {
                const int w = tid >> 6;     // 0: K[0,128), 1: K[128,256)
                #pragma unroll
                for (int i = 0; i < 4; ++i)
                    #pragma unroll
                    for (int u = 0; u < 4; ++u)
                        parts_gx[w][tr + 8 * i][tb + 4 * u] = accg[i][u];
            }
        } else if (tt > 0) {
            // ---- exchange on waves 2-3: poll own producer tag, fill 2 units ----
            const int p = tid - 128;       // 0..127; units 2p, 2p+1
            const int* my_tag = tags + ((g * 32 + (p >> 2)) << 1) + ((p & 3) >> 1);
            int v; int it = 0;
            for (;;) {
                asm volatile("global_load_dword %0, %1, off sc0 sc1\n\ts_waitcnt vmcnt(0)"
                             : "=&v"(v) : "v"(my_tag) : "memory");
                if (v >= tt) break;
                if (++it > 2) __builtin_amdgcn_s_sleep(2);
                if (it > (1 << 22)) break;   // failsafe (never hit when resident)
            }
            const float* hs = h_glob + ((size_t)(g * 2 + par)) * 4096 + (size_t)p * 32;
            float4 a0, a1, a2, a3, a4, a5, a6, a7;
            asm volatile(
                "global_load_dwordx4 %0, %8, off sc0 sc1\n\t"
                "global_load_dwordx4 %1, %8, off offset:16 sc0 sc1\n\t"
                "global_load_dwordx4 %2, %8, off offset:32 sc0 sc1\n\t"
                "global_load_dwordx4 %3, %8, off offset:48 sc0 sc1\n\t"
                "global_load_dwordx4 %4, %8, off offset:64 sc0 sc1\n\t"
                "global_load_dwordx4 %5, %8, off offset:80 sc0 sc1\n\t"
                "global_load_dwordx4 %6, %8, off offset:96 sc0 sc1\n\t"
                "global_load_dwordx4 %7, %8, off offset:112 sc0 sc1\n\t"
                "s_waitcnt vmcnt(0)"
                : "=&v"(a0), "=&v"(a1), "=&v"(a2), "=&v"(a3),
                  "=&v"(a4), "=&v"(a5), "=&v"(a6), "=&v"(a7)
                : "v"(hs) : "memory");
            __builtin_amdgcn_sched_barrier(0);
            const int u2 = p * 2;
            *reinterpret_cast<float2*>(&h_lds[ 0][u2]) = make_float2(a0.x, a4.x);
            *reinterpret_cast<float2*>(&h_lds[ 1][u2]) = make_float2(a0.y, a4.y);
            *reinterpret_cast<float2*>(&h_lds[ 2][u2]) = make_float2(a0.z, a4.z);
            *reinterpret_cast<float2*>(&h_lds[ 3][u2]) = make_float2(a0.w, a4.w);
            *reinterpret_cast<float2*>(&h_lds[ 4][u2]) = make_float2(a1.x, a5.x);
            *reinterpret_cast<float2*>(&h_lds[ 5][u2]) = make_float2(a1.y, a5.y);
            *reinterpret_cast<float2*>(&h_lds[ 6][u2]) = make_float2(a1.z, a5.z);
            *reinterpret_cast<float2*>(&h_lds[ 7][u2]) = make_float2(a1.w, a5.w);
            *reinterpret_cast<float2*>(&h_lds[ 8][u2]) = make_float2(a2.x, a6.x);
            *reinterpret_cast<float2*>(&h_lds[ 9][u2]) = make_float2(a2.y, a6.y);
            *reinterpret_cast<float2*>(&h_lds[10][u2]) = make_float2(a2.z, a6.z);
            *reinterpret_cast<float2*>(&h_lds[11][u2]) = make_float2(a2.w, a6.w);
            *reinterpret_cast<float2*>(&h_lds[12][u2]) = make_float2(a3.x, a7.x);
            *reinterpret_cast<float2*>(&h_lds[13][u2]) = make_float2(a3.y, a7.y);
            *reinterpret_cast<float2*>(&h_lds[14][u2]) = make_float2(a3.z, a7.z);
            *reinterpret_cast<float2*>(&h_lds[15][u2]) = make_float2(a3.w, a7.w);
        }
        __syncthreads();   // SYNC_A: h_lds ready, parts_gx ready

        // ---- stage emb for tt+1 (all threads; latency hides under hh dot) ----
        if (tt + 1 < Lv) {
            const int b = tid >> 4, cseg = tid & 15;
            const int t1 = d ? (Lv - 2 - tt) : (tt + 1);
            const int xv = x[(b0 + b) * Lv + t1];
            const float4* src = reinterpret_cast<const float4*>(embed + (size_t)xv * 256 + cseg * 16);
            float4 e0 = src[0], e1 = src[1], e2 = src[2], e3 = src[3];
            float4* dstp = reinterpret_cast<float4*>(&emb_lds[par ^ 1][b][cseg * 16]);
            dstp[0] = e0; dstp[1] = e1; dstp[2] = e2; dstp[3] = e3;
        }

        // ---- hh dot (all threads) ----
        if (tt > 0) {
            float acch[4][4];
            #pragma unroll
            for (int i = 0; i < 4; ++i)
                #pragma unroll
                for (int u = 0; u < 4; ++u) acch[i][u] = 0.f;
            #pragma unroll
            for (int m = 0; m < 8; ++m) {
                float4 hv[4];
                #pragma unroll
                for (int u = 0; u < 4; ++u)
                    hv[u] = *reinterpret_cast<const float4*>(&h_lds[tb + 4 * u][k0h + 4 * m]);
                #pragma unroll
                for (int i = 0; i < 4; ++i) {
                    const float4 wv = whh[i][m];
                    #pragma unroll
                    for (int u = 0; u < 4; ++u)
                        acch[i][u] += wv.x * hv[u].x + wv.y * hv[u].y + wv.z * hv[u].z + wv.w * hv[u].w;
                }
            }
            #pragma unroll
            for (int i = 0; i < 4; ++i)
                #pragma unroll
                for (int u = 0; u < 4; ++u)
                    acch[i][u] += __shfl_xor(acch[i][u], 32);
            if ((tid & 32) == 0) {
                const int w = tid >> 6;
                #pragma unroll
                for (int i = 0; i < 4; ++i)
                    #pragma unroll
                    for (int u = 0; u < 4; ++u)
                        parts_hh[w][tr + 8 * i][tb + 4 * u] = acch[i][u];
            }
        }
        __syncthreads();   // SYNC_B: parts_hh ready, emb_lds[par^1] ready

        // ---- pointwise on waves 0-1: unit u0+(tid>>4), batch b0+(tid&15) ----
        float hval = 0.f;
        if (tid < 128) {
            const int j  = tid >> 4;
            const int bb = tid & 15;
            float gv[4];
            #pragma unroll
            for (int q = 0; q < 4; ++q) {
                const int r = q * 8 + j;
                float s = parts_gx[0][r][bb] + parts_gx[1][r][bb] + bias_lds[r];
                if (tt > 0)
                    s += parts_hh[0][r][bb] + parts_hh[1][r][bb]
                       + parts_hh[2][r][bb] + parts_hh[3][r][bb];
                gv[q] = s;
            }
            creg = sigmoidf_(gv[1]) * creg + sigmoidf_(gv[0]) * tanhf(gv[2]);
            hval = sigmoidf_(gv[3]) * tanhf(creg);
            float* dst = h_glob + ((size_t)(g * 2 + (par ^ 1))) * 4096 + (u0 + j) * 16 + bb;
            asm volatile("global_store_dword %0, %1, off sc0 sc1"
                         :: "v"(dst), "v"(hval) : "memory");
        }
        // per-wave release: own wave's h stores drained -> publish this wave's tag
        asm volatile("s_waitcnt vmcnt(0)" ::: "memory");
        if ((tid & 63) == 0 && tid < 128) {
            int val = tt + 1;
            asm volatile("global_store_dword %0, %1, off sc0 sc1"
                         :: "v"(rel_tag), "v"(val) : "memory");
        }
        // h_hist store off the critical path (plain cached store)
        if (tid < 128) {
            const int j  = tid >> 4;
            const int bb = tid & 15;
            const int t_eff = d ? (Lv - 1 - tt) : tt;
            h_hist[((size_t)(b0 + bb) * Lv + t_eff) * 512 + d * 256 + u0 + j] = hval;
        }
    }
}

// emissions: em[l][b][j] = dot(h_hist[b][l][:512], Wout[j]) + bout[j]
__global__ __launch_bounds__(256) void emis_kernel(
    const float* __restrict__ h_hist, const float* __restrict__ Wout,
    const float* __restrict__ bout, float* __restrict__ em)
{
    const int l  = blockIdx.x >> 2;
    const int bg = blockIdx.x & 3;
    const int tid = threadIdx.x;
    __shared__ float w_lds[9][516];
    __shared__ float h_ldsx[16][512];

    for (int i = tid; i < 9 * 512; i += 256) w_lds[i >> 9][i & 511] = Wout[i];
    for (int i = tid; i < 16 * 128; i += 256) {
        const int bb = i >> 7; const int k = (i & 127) * 4;
        *reinterpret_cast<float4*>(&h_ldsx[bb][k]) =
            *reinterpret_cast<const float4*>(&h_hist[((size_t)(bg * 16 + bb) * 512 + l) * 512 + k]);
    }
    __syncthreads();

    const int bb = tid >> 4;
    const int j = tid & 15;
    if (j < 9) {
        float acc = bout[j];
        #pragma unroll 4
        for (int k = 0; k < 512; k += 4) {
            float4 hv = *reinterpret_cast<const float4*>(&h_ldsx[bb][k]);
            float4 wv = *reinterpret_cast<const float4*>(&w_lds[j][k]);
            acc += hv.x * wv.x + hv.y * wv.y + hv.z * wv.z + hv.w * wv.w;
        }
        em[((size_t)l * 64 + bg * 16 + bb) * 9 + j] = acc;
    }
}

__global__ __launch_bounds__(576) void viterbi_fwd(
    const float* __restrict__ em, const float* __restrict__ start,
    const float* __restrict__ trans, const float* __restrict__ endt,
    unsigned char* __restrict__ hist, int* __restrict__ last_tag,
    float* __restrict__ out_best)
{
    const int tid = threadIdx.x;
    const int b = tid / 9;
    const int j = tid - b * 9;
    __shared__ float sc[2][64][9];
    float t9[9];
    #pragma unroll
    for (int i = 0; i < 9; ++i) t9[i] = trans[i * 9 + j];

    sc[0][b][j] = start[j] + em[tid];
    float emv = em[(64 + b) * 9 + j];
    __syncthreads();
    for (int t = 1; t < 512; ++t) {
        float em_nxt = (t < 511) ? em[((t + 1) * 64 + b) * 9 + j] : 0.f;
        const int cur = t & 1, prv = cur ^ 1;
        float best = -1e30f; int arg = 0;
        #pragma unroll
        for (int i = 0; i < 9; ++i) {
            float v = sc[prv][b][i] + t9[i];
            if (v > best) { best = v; arg = i; }
        }
        best += emv;
        sc[cur][b][j] = best;
        hist[((size_t)b * 512 + t) * 9 + j] = (unsigned char)arg;
        __syncthreads();
        emv = em_nxt;
    }
    sc[1][b][j] += endt[j];
    __syncthreads();
    if (j == 0) {
        float best = -1e30f; int arg = 0;
        #pragma unroll
        for (int i = 0; i < 9; ++i) {
            float v = sc[1][b][i];
            if (v > best) { best = v; arg = i; }
        }
        out_best[b] = best;
        last_tag[b] = arg;
    }
}

__global__ __launch_bounds__(256) void backtrack(
    const unsigned char* __restrict__ hist, const int* __restrict__ last_tag,
    float* __restrict__ out_tags)
{
    const int b = blockIdx.x;
    const int tid = threadIdx.x;
    __shared__ __align__(16) unsigned char hl[512 * 9];
    const uint4* src = reinterpret_cast<const uint4*>(hist + (size_t)b * 512 * 9);
    uint4* dst = reinterpret_cast<uint4*>(hl);
    for (int i = tid; i < 512 * 9 / 16; i += 256) dst[i] = src[i];
    __syncthreads();
    if (tid == 0) {
        int tag = last_tag[b];
        out_tags[b * 512 + 511] = (float)tag;
        for (int t = 511; t >= 1; --t) {
            tag = hl[t * 9 + tag];
            out_tags[b * 512 + t - 1] = (float)tag;
        }
    }
}

extern "C" void kernel_launch(void* const* d_in, const int* in_sizes, int n_in,
                              void* d_out, int out_size, void* d_ws, size_t ws_size,
                              hipStream_t stream)
{
    const int*   x     = (const int*)d_in[0];
    const float* embed = (const float*)d_in[1];
    const float* Wih_f = (const float*)d_in[2];
    const float* Whh_f = (const float*)d_in[3];
    const float* bf    = (const float*)d_in[4];
    const float* Wih_b = (const float*)d_in[5];
    const float* Whh_b = (const float*)d_in[6];
    const float* bb    = (const float*)d_in[7];
    const float* Wout  = (const float*)d_in[8];
    const float* bout  = (const float*)d_in[9];
    const float* start = (const float*)d_in[10];
    const float* trans = (const float*)d_in[11];
    const float* endt  = (const float*)d_in[12];

    char* ws = (char*)d_ws;
    float* h_glob  = (float*)ws;                        // 262144 B
    int*   tags    = (int*)(ws + 262144);               // 2048 B
    float* h_hist  = (float*)(ws + 267264);             // 67108864 B
    float* em      = (float*)(ws + 267264 + 67108864);  // @67376128, 1179648 B
    int*   last_tag = (int*)(ws + 68555776);            // 256 B
    unsigned char* hist = (unsigned char*)(ws + 68556032); // 294912 B

    float* out = (float*)d_out;   // [64*512 tags][64 best], all f32

    hipMemsetAsync(tags, 0, 2048, stream);        // tags = 0

    lstm_persist<<<256, 256, 0, stream>>>(x, embed, Wih_f, Whh_f, bf,
                                          Wih_b, Whh_b, bb,
                                          h_glob, tags, h_hist);
    emis_kernel<<<2048, 256, 0, stream>>>(h_hist, Wout, bout, em);
    viterbi_fwd<<<1, 576, 0, stream>>>(em, start, trans, endt, hist, last_tag, out + 64 * 512);
    backtrack<<<64, 256, 0, stream>>>(hist, last_tag, out);
}